// Round 9
// baseline (1198.259 us; speedup 1.0000x reference)
//
#include <hip/hip_runtime.h>
#include <hip/hip_bf16.h>
#include <hip/hip_fp16.h>

// Problem constants (fixed by the reference's setup_inputs)
#define N_ITEM 80000
#define N_USER 20000
#define NN     100000   // N_ITEM + N_USER
#define NE     1000000  // edges
#define SCAN_T 1024
#define SCAN_TILES ((NN + SCAN_T - 1) / SCAN_T)   // 98

typedef __hip_bfloat16 bf16;

__device__ __forceinline__ float b2f(bf16 v) { return __bfloat162float(v); }
__device__ __forceinline__ bf16  f2b(float v) { return __float2bfloat16(v); }
__device__ __forceinline__ float bits2f(unsigned short h) {
    return __uint_as_float(((unsigned)h) << 16);
}
__device__ __forceinline__ float leaky(float v) { return v >= 0.f ? v : 0.01f * v; }

// dtype-adaptive scalar load
template<typename T>
__device__ __forceinline__ float ldT(const void* p, size_t i);
template<> __device__ __forceinline__ float ldT<float>(const void* p, size_t i) {
    return ((const float*)p)[i];
}
template<> __device__ __forceinline__ float ldT<bf16>(const void* p, size_t i) {
    return b2f(((const bf16*)p)[i]);
}
// dtype-adaptive float4 load/store (i multiple of 4)
template<typename T>
__device__ __forceinline__ float4 ldT4(const void* p, size_t i);
template<> __device__ __forceinline__ float4 ldT4<float>(const void* p, size_t i) {
    return *(const float4*)((const float*)p + i);
}
template<> __device__ __forceinline__ float4 ldT4<bf16>(const void* p, size_t i) {
    ushort4 u = *(const ushort4*)((const unsigned short*)p + i);
    return make_float4(bits2f(u.x), bits2f(u.y), bits2f(u.z), bits2f(u.w));
}
template<typename T>
__device__ __forceinline__ void stT4(void* p, size_t i, float4 v);
template<> __device__ __forceinline__ void stT4<float>(void* p, size_t i, float4 v) {
    *(float4*)((float*)p + i) = v;
}
template<> __device__ __forceinline__ void stT4<bf16>(void* p, size_t i, float4 v) {
    bf16 b0 = f2b(v.x), b1 = f2b(v.y), b2 = f2b(v.z), b3 = f2b(v.w);
    ushort4 u = make_ushort4(*(unsigned short*)&b0, *(unsigned short*)&b1,
                             *(unsigned short*)&b2, *(unsigned short*)&b3);
    *(ushort4*)((unsigned short*)p + i) = u;
}
__device__ __forceinline__ float4 ld4f(const float* p, size_t i) {
    return *(const float4*)(p + i);
}
// bf16 xw-table load/store (ushort bits)
__device__ __forceinline__ float4 ld4b(const unsigned short* p, size_t i) {
    ushort4 u = *(const ushort4*)(p + i);
    return make_float4(bits2f(u.x), bits2f(u.y), bits2f(u.z), bits2f(u.w));
}
__device__ __forceinline__ void st4b(unsigned short* p, size_t i, float4 v) {
    bf16 b0 = f2b(v.x), b1 = f2b(v.y), b2 = f2b(v.z), b3 = f2b(v.w);
    ushort4 u = make_ushort4(*(unsigned short*)&b0, *(unsigned short*)&b1,
                             *(unsigned short*)&b2, *(unsigned short*)&b3);
    *(ushort4*)(p + i) = u;
}
// f16 (IEEE half) x_hat table: better mantissa than bf16, same 2 B
__device__ __forceinline__ float4 ld4h(const unsigned short* p, size_t i) {
    ushort4 u = *(const ushort4*)(p + i);
    __half h0, h1, h2, h3;
    *(unsigned short*)&h0 = u.x; *(unsigned short*)&h1 = u.y;
    *(unsigned short*)&h2 = u.z; *(unsigned short*)&h3 = u.w;
    return make_float4(__half2float(h0), __half2float(h1),
                       __half2float(h2), __half2float(h3));
}
__device__ __forceinline__ void st4h(unsigned short* p, size_t i, float4 v) {
    __half h0 = __float2half(v.x), h1 = __float2half(v.y);
    __half h2 = __float2half(v.z), h3 = __float2half(v.w);
    ushort4 u = make_ushort4(*(unsigned short*)&h0, *(unsigned short*)&h1,
                             *(unsigned short*)&h2, *(unsigned short*)&h3);
    *(ushort4*)(p + i) = u;
}

// full 64-lane wave sum (float)
__device__ __forceinline__ float wred(float v) {
    for (int o = 32; o; o >>= 1) v += __shfl_xor(v, o, 64);
    return v;
}
// 16-lane group sum
__device__ __forceinline__ float gred16(float v) {
    for (int o = 8; o; o >>= 1) v += __shfl_xor(v, o, 64);
    return v;
}
// 64-lane inclusive scan (int)
__device__ __forceinline__ int wscan(int v, int lane) {
    for (int o = 1; o < 64; o <<= 1) {
        int t = __shfl_up(v, o, 64);
        v += (lane >= o) ? t : 0;
    }
    return v;
}

// ---- storage-dtype detection (bf16 vs f32 harness buffers) ----
__global__ void k_detect(const unsigned short* __restrict__ w, int* __restrict__ mode) {
    __shared__ int cnt[256];
    int bad = 0;
    for (int i = threadIdx.x; i < 4096; i += 256) {
        unsigned e = (w[i] >> 7) & 0xFFu;
        bad += (e == 0u || e == 0xFFu) ? 1 : 0;
    }
    cnt[threadIdx.x] = bad;
    __syncthreads();
    if (threadIdx.x == 0) {
        int t = 0;
        for (int k = 0; k < 256; k++) t += cnt[k];
        mode[0] = (t > 0) ? 1 : 0;   // 1 = float32 storage, 0 = bf16 storage
    }
}

// ---- transpose + f32-promote row-major weights ----
__global__ void k_prep_w(const void* umw, const void* lw1, const void* gw1,
                         const void* lw2, const void* gw2,
                         float* umwT, float* wT, const int* mode) {
    int t = blockIdx.x * 256 + threadIdx.x;   // 0 .. 24575
    bool f32m = (*mode != 0);
    if (t < 8192) {
        int j = t >> 7, k = t & 127;
        float v = f32m ? ldT<float>(umw, t) : ldT<bf16>(umw, t);
        umwT[k * 64 + j] = v;
    } else {
        int u = t - 8192;
        int m = u >> 12;          // 0..3
        int r = u & 4095;
        int j = r >> 6, k = r & 63;
        const void* srcp = (m == 0) ? lw1 : (m == 1) ? gw1 : (m == 2) ? lw2 : gw2;
        float v = f32m ? ldT<float>(srcp, r) : ldT<bf16>(srcp, r);
        wT[m * 4096 + k * 64 + j] = v;
    }
}

// ---- degree counts: out-degree over src (gate) + in-degree over dst (CSR) ----
__global__ void k_deg(const int* __restrict__ src, const int* __restrict__ dst,
                      int* __restrict__ deg, int* __restrict__ cnt) {
    int e = blockIdx.x * blockDim.x + threadIdx.x;
    if (e < NE) {
        atomicAdd(&deg[src[e]], 1);
        atomicAdd(&cnt[dst[e]], 1);
    }
}

// ---- parallel scan, pass 1: per-tile sums (+ fused dinv = rsqrt(deg)) ----
__global__ void k_scan_sum(const int* __restrict__ cnt, const int* __restrict__ deg,
                           float* __restrict__ dinv, int* __restrict__ tsum) {
    __shared__ int wsum[16];
    int i = blockIdx.x * SCAN_T + threadIdx.x;
    int lane = threadIdx.x & 63, wid = threadIdx.x >> 6;
    int v = (i < NN) ? cnt[i] : 0;
    if (i < NN) dinv[i] = rsqrtf((float)max(deg[i], 1));   // fused (was k_dinv)
    float s = wred((float)v);               // exact: counts < 2^24
    if (lane == 0) wsum[wid] = (int)s;
    __syncthreads();
    if (threadIdx.x == 0) {
        int t = 0;
        #pragma unroll
        for (int k = 0; k < 16; k++) t += wsum[k];
        tsum[blockIdx.x] = t;
    }
}

// ---- pass 2: exclusive scan of the tile sums (1 block) ----
__global__ void k_scan_tiles(const int* __restrict__ tsum, int* __restrict__ toff) {
    __shared__ int wsum[16];
    int lane = threadIdx.x & 63, wid = threadIdx.x >> 6;
    int v = (threadIdx.x < SCAN_TILES) ? tsum[threadIdx.x] : 0;
    int inc = wscan(v, lane);
    if (lane == 63) wsum[wid] = inc;
    __syncthreads();
    if (wid == 0) {
        int ws = (lane < 16) ? wsum[lane] : 0;
        int wi = wscan(ws, lane);
        if (lane < 16) wsum[lane] = wi - ws;   // exclusive wave offsets
    }
    __syncthreads();
    if (threadIdx.x < SCAN_TILES) toff[threadIdx.x] = inc - v + wsum[wid];
}

// ---- pass 3: block-local exclusive scan + tile offset -> csr_off, cursor ----
__global__ void k_scan_out(const int* __restrict__ cnt, const int* __restrict__ toff,
                           int* __restrict__ csr_off, int* __restrict__ cursor) {
    __shared__ int wsum[16];
    int i = blockIdx.x * SCAN_T + threadIdx.x;
    int lane = threadIdx.x & 63, wid = threadIdx.x >> 6;
    int v = (i < NN) ? cnt[i] : 0;
    int inc = wscan(v, lane);
    if (lane == 63) wsum[wid] = inc;
    __syncthreads();
    if (wid == 0) {
        int ws = (lane < 16) ? wsum[lane] : 0;
        int wi = wscan(ws, lane);
        if (lane < 16) wsum[lane] = wi - ws;
    }
    __syncthreads();
    int excl = inc - v + wsum[wid] + toff[blockIdx.x];
    if (i < NN) { csr_off[i] = excl; cursor[i] = excl; }
    if (i == NN - 1) csr_off[NN] = excl + v;   // == NE
}

// ---- scatter edges into dst-sorted CSR ----
__global__ void k_scatter(const int* __restrict__ src, const int* __restrict__ dst,
                          int* __restrict__ cursor, int* __restrict__ csr_src) {
    int e = blockIdx.x * blockDim.x + threadIdx.x;
    if (e < NE) {
        int pos = atomicAdd(&cursor[dst[e]], 1);
        csr_src[pos] = src[e];
    }
}

// ---- k_front_items: hop-1 front end for item nodes.
//      normalize(feat[i]) in registers -> dual matmul from LDS Wg/lT ->
//      xw (bf16) + x_hat (f16). Replaces prep_items + k_pre-hop1 for items;
//      the x/buf0 HBM round-trip is gone. Grid = 80000/16 = 5000 exact.
template<typename T>
__device__ __forceinline__ void front_items_body(float4* __restrict__ gsW,
                                                 float4* __restrict__ gsL,
                                                 const void* __restrict__ feat,
                                                 const void* __restrict__ Wg,
                                                 const float* __restrict__ lT,
                                                 const void* __restrict__ lb,
                                                 const void* __restrict__ id_emb,
                                                 unsigned short* __restrict__ xw,
                                                 unsigned short* __restrict__ xhat) {
    int lane = threadIdx.x & 63, wid = threadIdx.x >> 6;
    int sl = lane & 15;
    int i = blockIdx.x * 16 + (wid << 2) + (lane >> 4);   // < 80000 (grid exact)
    // stage Wg + lT -> LDS
    #pragma unroll
    for (int t = 0; t < 4; t++) {
        int idx = threadIdx.x + t * 256;
        gsW[idx] = ldT4<T>(Wg, (size_t)idx * 4);
        gsL[idx] = ld4f(lT, (size_t)idx * 4);
    }
    size_t rb = (size_t)i * 64 + sl * 4;
    float4 v = ldT4<T>(feat, rb);
    float ss = gred16(v.x * v.x + v.y * v.y + v.z * v.z + v.w * v.w);
    float inv = 1.f / fmaxf(sqrtf(ss), 1e-12f);
    float4 xv = make_float4(v.x * inv, v.y * inv, v.z * inv, v.w * inv);
    float4 lb4 = ldT4<T>(lb, sl * 4);
    float4 id4 = ldT4<T>(id_emb, rb);
    __syncthreads();
    float4 accw = make_float4(0.f, 0.f, 0.f, 0.f);
    float4 accl = make_float4(0.f, 0.f, 0.f, 0.f);
    int gbase = lane & 48;
    #pragma unroll
    for (int kk = 0; kk < 16; kk++) {
        int srcl = gbase | kk;
        float xb[4];
        xb[0] = __shfl(xv.x, srcl, 64);
        xb[1] = __shfl(xv.y, srcl, 64);
        xb[2] = __shfl(xv.z, srcl, 64);
        xb[3] = __shfl(xv.w, srcl, 64);
        #pragma unroll
        for (int q = 0; q < 4; q++) {
            int wb = (kk * 4 + q) * 16 + sl;
            float4 w4 = gsW[wb];
            float4 l4 = gsL[wb];
            accw.x += xb[q] * w4.x; accw.y += xb[q] * w4.y;
            accw.z += xb[q] * w4.z; accw.w += xb[q] * w4.w;
            accl.x += xb[q] * l4.x; accl.y += xb[q] * l4.y;
            accl.z += xb[q] * l4.z; accl.w += xb[q] * l4.w;
        }
    }
    st4b(xw, rb, accw);
    float4 xh;
    xh.x = leaky(accl.x + lb4.x) + id4.x;
    xh.y = leaky(accl.y + lb4.y) + id4.y;
    xh.z = leaky(accl.z + lb4.z) + id4.z;
    xh.w = leaky(accl.w + lb4.w) + id4.w;
    st4h(xhat, rb, xh);
}
__global__ void k_front_items(const void* feat, const void* Wg, const float* lT,
                              const void* lb, const void* id_emb,
                              unsigned short* xw, unsigned short* xhat,
                              const int* mode) {
    __shared__ float4 gsW[1024];           // 16 KB (wrapper-hoisted: no dup)
    __shared__ float4 gsL[1024];           // 16 KB
    if (*mode) front_items_body<float>(gsW, gsL, feat, Wg, lT, lb, id_emb, xw, xhat);
    else       front_items_body<bf16>(gsW, gsL, feat, Wg, lT, lb, id_emb, xw, xhat);
}

// ---- k_front_users: hop-1 front end for user nodes.
//      LDS-staged umwT MLP (tanh + normalize) -> restage Wg/lT -> dual matmul.
//      Replaces prep_users + k_pre-hop1 for users. Grid = 20000/16 = 1250 exact.
//      Barriers: stage umwT / done-reading-umwT / Wg,lT staged (uniform per block).
template<typename T>
__device__ __forceinline__ void front_users_body(float4* __restrict__ gsW,
                                                 float4* __restrict__ gsL,
                                                 const void* __restrict__ uf,
                                                 const float* __restrict__ umwT,
                                                 const void* __restrict__ umb,
                                                 const void* __restrict__ Wg,
                                                 const float* __restrict__ lT,
                                                 const void* __restrict__ lb,
                                                 const void* __restrict__ id_emb,
                                                 unsigned short* __restrict__ xw,
                                                 unsigned short* __restrict__ xhat) {
    int lane = threadIdx.x & 63, wid = threadIdx.x >> 6;
    int sl = lane & 15;
    int u = blockIdx.x * 16 + (wid << 2) + (lane >> 4);   // < 20000 (grid exact)
    int i = N_ITEM + u;
    int gbase = lane & 48;
    // stage umwT (128x64 f32 = 32 KB): k=0..63 -> gsW, k=64..127 -> gsL
    #pragma unroll
    for (int t = 0; t < 4; t++) {
        int idx = threadIdx.x + t * 256;
        gsW[idx] = ld4f(umwT, (size_t)idx * 4);
        gsL[idx] = ld4f(umwT, (size_t)(idx + 1024) * 4);
    }
    __syncthreads();
    size_t ub = (size_t)u * 128;
    float4 ufa = ldT4<T>(uf, ub + sl * 8);       // lane sl holds k = sl*8..sl*8+7
    float4 ufb = ldT4<T>(uf, ub + sl * 8 + 4);
    float4 acc = ldT4<T>(umb, sl * 4);
    #pragma unroll
    for (int kk = 0; kk < 16; kk++) {
        int srcl = gbase | kk;
        float f0 = __shfl(ufa.x, srcl, 64);
        float f1 = __shfl(ufa.y, srcl, 64);
        float f2 = __shfl(ufa.z, srcl, 64);
        float f3 = __shfl(ufa.w, srcl, 64);
        float f4 = __shfl(ufb.x, srcl, 64);
        float f5 = __shfl(ufb.y, srcl, 64);
        float f6 = __shfl(ufb.z, srcl, 64);
        float f7 = __shfl(ufb.w, srcl, 64);
        // k = kk*8 + r ; kk<8 -> gsW, kk>=8 -> gsL (compile-time per unrolled kk)
        const float4* bank = (kk < 8) ? gsW : gsL;
        int kb = (kk & 7) * 8;
        float4 w0 = bank[(kb + 0) * 16 + sl];
        float4 w1 = bank[(kb + 1) * 16 + sl];
        float4 w2 = bank[(kb + 2) * 16 + sl];
        float4 w3 = bank[(kb + 3) * 16 + sl];
        float4 w4 = bank[(kb + 4) * 16 + sl];
        float4 w5 = bank[(kb + 5) * 16 + sl];
        float4 w6 = bank[(kb + 6) * 16 + sl];
        float4 w7 = bank[(kb + 7) * 16 + sl];
        acc.x += f0*w0.x + f1*w1.x + f2*w2.x + f3*w3.x
               + f4*w4.x + f5*w5.x + f6*w6.x + f7*w7.x;
        acc.y += f0*w0.y + f1*w1.y + f2*w2.y + f3*w3.y
               + f4*w4.y + f5*w5.y + f6*w6.y + f7*w7.y;
        acc.z += f0*w0.z + f1*w1.z + f2*w2.z + f3*w3.z
               + f4*w4.z + f5*w5.z + f6*w6.z + f7*w7.z;
        acc.w += f0*w0.w + f1*w1.w + f2*w2.w + f3*w3.w
               + f4*w4.w + f5*w5.w + f6*w6.w + f7*w7.w;
    }
    float4 v = make_float4(tanhf(acc.x), tanhf(acc.y), tanhf(acc.z), tanhf(acc.w));
    float ss = gred16(v.x * v.x + v.y * v.y + v.z * v.z + v.w * v.w);
    float inv = 1.f / fmaxf(sqrtf(ss), 1e-12f);
    float4 xv = make_float4(v.x * inv, v.y * inv, v.z * inv, v.w * inv);
    __syncthreads();                       // everyone done reading umwT
    // restage Wg + lT -> LDS
    #pragma unroll
    for (int t = 0; t < 4; t++) {
        int idx = threadIdx.x + t * 256;
        gsW[idx] = ldT4<T>(Wg, (size_t)idx * 4);
        gsL[idx] = ld4f(lT, (size_t)idx * 4);
    }
    size_t rb = (size_t)i * 64 + sl * 4;
    float4 lb4 = ldT4<T>(lb, sl * 4);
    float4 id4 = ldT4<T>(id_emb, rb);
    __syncthreads();
    float4 accw = make_float4(0.f, 0.f, 0.f, 0.f);
    float4 accl = make_float4(0.f, 0.f, 0.f, 0.f);
    #pragma unroll
    for (int kk = 0; kk < 16; kk++) {
        int srcl = gbase | kk;
        float xb[4];
        xb[0] = __shfl(xv.x, srcl, 64);
        xb[1] = __shfl(xv.y, srcl, 64);
        xb[2] = __shfl(xv.z, srcl, 64);
        xb[3] = __shfl(xv.w, srcl, 64);
        #pragma unroll
        for (int q = 0; q < 4; q++) {
            int wb = (kk * 4 + q) * 16 + sl;
            float4 w4 = gsW[wb];
            float4 l4 = gsL[wb];
            accw.x += xb[q] * w4.x; accw.y += xb[q] * w4.y;
            accw.z += xb[q] * w4.z; accw.w += xb[q] * w4.w;
            accl.x += xb[q] * l4.x; accl.y += xb[q] * l4.y;
            accl.z += xb[q] * l4.z; accl.w += xb[q] * l4.w;
        }
    }
    st4b(xw, rb, accw);
    float4 xh;
    xh.x = leaky(accl.x + lb4.x) + id4.x;
    xh.y = leaky(accl.y + lb4.y) + id4.y;
    xh.z = leaky(accl.z + lb4.z) + id4.z;
    xh.w = leaky(accl.w + lb4.w) + id4.w;
    st4h(xhat, rb, xh);
}
__global__ void k_front_users(const void* uf, const float* umwT, const void* umb,
                              const void* Wg, const float* lT, const void* lb,
                              const void* id_emb,
                              unsigned short* xw, unsigned short* xhat,
                              const int* mode) {
    __shared__ float4 gsW[1024];           // 16 KB (wrapper-hoisted: no dup)
    __shared__ float4 gsL[1024];           // 16 KB
    if (*mode) front_users_body<float>(gsW, gsL, uf, umwT, umb, Wg, lT, lb,
                                       id_emb, xw, xhat);
    else       front_users_body<bf16>(gsW, gsL, uf, umwT, umb, Wg, lT, lb,
                                      id_emb, xw, xhat);
}

// ---- k_pre (hop 2): xw = xin @ Wg -> bf16, x_hat -> f16; LDS weights ----
template<typename T>
__device__ __forceinline__ void pre_body(float4* __restrict__ gsW,
                                         float4* __restrict__ gsL,
                                         const float* __restrict__ xin,
                                         const void* __restrict__ Wg,
                                         const float* __restrict__ lT,
                                         const void* __restrict__ lb,
                                         const void* __restrict__ id_emb,
                                         unsigned short* __restrict__ xw,
                                         unsigned short* __restrict__ xhat) {
    int lane = threadIdx.x & 63, wid = threadIdx.x >> 6;
    int sl = lane & 15;
    int i = blockIdx.x * 16 + (wid << 2) + (lane >> 4);   // always < NN (grid exact)
    // stage both weight matrices -> LDS
    #pragma unroll
    for (int t = 0; t < 4; t++) {
        int idx = threadIdx.x + t * 256;
        gsW[idx] = ldT4<T>(Wg, (size_t)idx * 4);
        gsL[idx] = ld4f(lT, (size_t)idx * 4);
    }
    size_t rb = (size_t)i * 64 + sl * 4;
    float4 xv = ld4f(xin, rb);
    float4 lb4 = ldT4<T>(lb, sl * 4);
    float4 id4 = ldT4<T>(id_emb, rb);
    __syncthreads();
    float4 accw = make_float4(0.f, 0.f, 0.f, 0.f);
    float4 accl = make_float4(0.f, 0.f, 0.f, 0.f);
    int gbase = lane & 48;
    #pragma unroll
    for (int kk = 0; kk < 16; kk++) {
        int srcl = gbase | kk;
        float xb[4];
        xb[0] = __shfl(xv.x, srcl, 64);
        xb[1] = __shfl(xv.y, srcl, 64);
        xb[2] = __shfl(xv.z, srcl, 64);
        xb[3] = __shfl(xv.w, srcl, 64);
        #pragma unroll
        for (int q = 0; q < 4; q++) {
            int wb = (kk * 4 + q) * 16 + sl;
            float4 w4 = gsW[wb];
            float4 l4 = gsL[wb];
            accw.x += xb[q] * w4.x; accw.y += xb[q] * w4.y;
            accw.z += xb[q] * w4.z; accw.w += xb[q] * w4.w;
            accl.x += xb[q] * l4.x; accl.y += xb[q] * l4.y;
            accl.z += xb[q] * l4.z; accl.w += xb[q] * l4.w;
        }
    }
    st4b(xw, rb, accw);              // bf16 gather table
    float4 xh;
    xh.x = leaky(accl.x + lb4.x) + id4.x;
    xh.y = leaky(accl.y + lb4.y) + id4.y;
    xh.z = leaky(accl.z + lb4.z) + id4.z;
    xh.w = leaky(accl.w + lb4.w) + id4.w;
    st4h(xhat, rb, xh);              // f16 x_hat table (err ~1e-4, negligible)
}
__global__ void k_pre(const float* xin, const void* Wg, const float* lT,
                      const void* lb, const void* id_emb,
                      unsigned short* xw, unsigned short* xhat, const int* mode) {
    __shared__ float4 gsW[1024];           // 16 KB (single allocation)
    __shared__ float4 gsL[1024];           // 16 KB
    if (*mode) pre_body<float>(gsW, gsL, xin, Wg, lT, lb, id_emb, xw, xhat);
    else       pre_body<bf16>(gsW, gsL, xin, Wg, lT, lb, id_emb, xw, xhat);
}

// ---- fused GAT layer: byte-identical to the round-8 proven version ----
template<typename T>
__device__ __forceinline__ void gat_body(float4* __restrict__ gs,
                                         const unsigned short* __restrict__ xw,
                                         const unsigned short* __restrict__ xhat,
                                         const int* __restrict__ csr_off,
                                         const int* __restrict__ csr_src,
                                         const float* __restrict__ dinv,
                                         const float* __restrict__ gTg,
                                         const void* gb,
                                         float* __restrict__ xnext, void* out,
                                         int off_out) {
    int lane = threadIdx.x & 63, wid = threadIdx.x >> 6;
    int sl = lane & 15;
    int i = blockIdx.x * 16 + (wid << 2) + (lane >> 4);   // always < NN (grid exact)
    size_t rb = (size_t)i * 64 + sl * 4;
    // stage gT -> LDS (completes long before the epilogue barrier)
    #pragma unroll
    for (int t = 0; t < 4; t++)
        gs[threadIdx.x + t * 256] = ((const float4*)gTg)[threadIdx.x + t * 256];

    float4 xd = ld4b(xw, rb);
    int e0 = csr_off[i], e1 = csr_off[i + 1];
    int cnt = e1 - e0;
    float m = -1e30f, l = 0.f;
    float4 acc = make_float4(0.f, 0.f, 0.f, 0.f);
    // 2-deep software pipeline over the segment's gathers (round-0 exact)
    float4 xsA = make_float4(0.f, 0.f, 0.f, 0.f), xsB = xsA;
    float dA = 1.f, dB = 1.f;
    if (cnt > 0) {
        int s0 = csr_src[e0];
        xsA = ld4b(xw, (size_t)s0 * 64 + sl * 4);
        dA = dinv[s0];
    }
    if (cnt > 1) {
        int s1 = csr_src[e0 + 1];
        xsB = ld4b(xw, (size_t)s1 * 64 + sl * 4);
        dB = dinv[s1];
    }
    for (int t = 0; t < cnt; ++t) {
        float4 xs = xsA; float dv = dA;
        xsA = xsB; dA = dB;
        if (t + 2 < cnt) {
            int sn = csr_src[e0 + t + 2];
            xsB = ld4b(xw, (size_t)sn * 64 + sl * 4);
            dB = dinv[sn];
        }
        float p = xd.x * xs.x + xd.y * xs.y + xd.z * xs.z + xd.w * xs.w;
        float inner = gred16(p);                   // full 64-ch dot
        float gate = 1.f / (1.f + __expf(-dv * inner));
        float logit = inner * gate;
        float mn = fmaxf(m, logit);
        float sc = __expf(m - mn);                 // ==0 on first edge (m=-1e30)
        float w  = __expf(logit - mn);
        acc.x = acc.x * sc + w * xs.x;
        acc.y = acc.y * sc + w * xs.y;
        acc.z = acc.z * sc + w * xs.z;
        acc.w = acc.w * sc + w * xs.w;
        l = l * sc + w;
        m = mn;
    }
    float linv = 1.f / (l + 1e-16f);               // deg-0 dst: h = 0 (== ref)
    float4 hv = make_float4(leaky(acc.x * linv), leaky(acc.y * linv),
                            leaky(acc.z * linv), leaky(acc.w * linv));
    __syncthreads();                               // gs ready (stores long done)
    // epilogue: accg = hv @ g.T from LDS weights
    float4 accg = make_float4(0.f, 0.f, 0.f, 0.f);
    int gbase = lane & 48;
    #pragma unroll
    for (int kk = 0; kk < 16; kk++) {
        int srcl = gbase | kk;
        float hb[4];
        hb[0] = __shfl(hv.x, srcl, 64);
        hb[1] = __shfl(hv.y, srcl, 64);
        hb[2] = __shfl(hv.z, srcl, 64);
        hb[3] = __shfl(hv.w, srcl, 64);
        #pragma unroll
        for (int q = 0; q < 4; q++) {
            float4 g4 = gs[(kk * 4 + q) * 16 + sl];
            accg.x += hb[q] * g4.x; accg.y += hb[q] * g4.y;
            accg.z += hb[q] * g4.z; accg.w += hb[q] * g4.w;
        }
    }
    float4 gb4 = ldT4<T>(gb, sl * 4);
    float4 xh4 = ld4h(xhat, rb);
    float4 xn;
    xn.x = leaky(accg.x + gb4.x + xh4.x);
    xn.y = leaky(accg.y + gb4.y + xh4.y);
    xn.z = leaky(accg.z + gb4.z + xh4.z);
    xn.w = leaky(accg.w + gb4.w + xh4.w);
    if (xnext) *(float4*)(xnext + rb) = xn;
    stT4<T>(out, (size_t)i * 128 + off_out + sl * 4, xn);
}
__global__ void k_gat(const unsigned short* xw, const unsigned short* xhat,
                      const int* csr_off, const int* csr_src, const float* dinv,
                      const float* gTg, const void* gb,
                      float* xnext, void* out, int off_out, const int* mode) {
    __shared__ float4 gs[1024];            // 16 KB (single allocation)
    if (*mode) gat_body<float>(gs, xw, xhat, csr_off, csr_src, dinv, gTg, gb,
                               xnext, out, off_out);
    else       gat_body<bf16>(gs, xw, xhat, csr_off, csr_src, dinv, gTg, gb,
                              xnext, out, off_out);
}

extern "C" void kernel_launch(void* const* d_in, const int* in_sizes, int n_in,
                              void* d_out, int out_size, void* d_ws, size_t ws_size,
                              hipStream_t stream) {
    const void* feat   = d_in[0];
    const void* uf     = d_in[1];
    const void* id_emb = d_in[2];
    const void* umw    = d_in[3];
    const void* umb    = d_in[4];
    const void* gat1   = d_in[5];
    const void* lin1b  = d_in[7];
    const void* g1b    = d_in[9];
    const void* gat2   = d_in[10];
    const void* lin2b  = d_in[12];
    const void* g2b    = d_in[14];
    const int*  ei     = (const int*)d_in[15];
    const int* src = ei;
    const int* dst = ei + NE;

    // workspace layout (~83 MB; buf0 slot unused now, kept for layout stability)
    int*      mode   = (int*)d_ws;                       // 16 B slot
    int*      deg    = (int*)((char*)d_ws + 16);         // NN
    int*      cnt    = deg + NN;                         // NN (adjacent: one memset)
    int*      cursor = cnt + NN;                         // NN
    int*      csr_off = cursor + NN;                     // NN+16
    int*      tsum   = csr_off + NN + 16;                // 128
    int*      toff   = tsum + 128;                       // 128
    float*    dinv   = (float*)(toff + 128);             // NN
    float*    umwT   = dinv + NN;                        // 8192
    float*    wT     = umwT + 8192;                      // 4 x 4096
    int*      csr_src = (int*)(wT + 4 * 4096);           // NE
    float*    buf0   = (float*)(csr_src + NE);           // (unused)
    float*    buf2   = buf0 + (size_t)NN * 64;           // x1    (25.6 MB f32)
    unsigned short* xwb   = (unsigned short*)(buf2 + (size_t)NN * 64); // 12.8 MB bf16
    unsigned short* xhath = xwb + (size_t)NN * 64;       // 12.8 MB f16 x_hat

    k_detect<<<1, 256, 0, stream>>>((const unsigned short*)feat, mode);
    k_prep_w<<<96, 256, 0, stream>>>(umw, d_in[6], d_in[8], d_in[11], d_in[13],
                                     umwT, wT, mode);
    hipMemsetAsync(deg, 0, 2 * NN * 4, stream);          // deg + cnt (adjacent)
    k_deg<<<(NE + 255) / 256, 256, 0, stream>>>(src, dst, deg, cnt);
    k_scan_sum<<<SCAN_TILES, SCAN_T, 0, stream>>>(cnt, deg, dinv, tsum);
    k_scan_tiles<<<1, SCAN_T, 0, stream>>>(tsum, toff);
    k_scan_out<<<SCAN_TILES, SCAN_T, 0, stream>>>(cnt, toff, csr_off, cursor);
    k_scatter<<<(NE + 255) / 256, 256, 0, stream>>>(src, dst, cursor, csr_src);

    const float* lT1 = wT;
    const float* gT1 = wT + 4096;
    const float* lT2 = wT + 8192;
    const float* gT2 = wT + 12288;

    int nb = NN / 16;   // 6250 exactly (NN % 16 == 0) -> barriers safe

    // hop 1: feat/uf -> {xw, xhat} directly (split fused front end)
    k_front_items<<<N_ITEM / 16, 256, 0, stream>>>(feat, gat1, lT1, lin1b,
                                                   id_emb, xwb, xhath, mode);
    k_front_users<<<N_USER / 16, 256, 0, stream>>>(uf, umwT, umb, gat1, lT1,
                                                   lin1b, id_emb, xwb, xhath,
                                                   mode);
    k_gat<<<nb, 256, 0, stream>>>(xwb, xhath, csr_off, csr_src, dinv,
                                  gT1, g1b, buf2, d_out, 0, mode);
    // hop 2: x1(buf2) -> {xw, xhat} -> out cols 64..127 (x2 store skipped)
    k_pre<<<nb, 256, 0, stream>>>(buf2, gat2, lT2, lin2b, id_emb,
                                  xwb, xhath, mode);
    k_gat<<<nb, 256, 0, stream>>>(xwb, xhath, csr_off, csr_src, dinv,
                                  gT2, g2b, nullptr, d_out, 64, mode);
}

// Round 10
// 558.904 us; speedup vs baseline: 2.1439x; 2.1439x over previous
//
#include <hip/hip_runtime.h>
#include <hip/hip_bf16.h>
#include <hip/hip_fp16.h>

// Problem constants (fixed by the reference's setup_inputs)
#define N_ITEM 80000
#define N_USER 20000
#define NN     100000   // N_ITEM + N_USER
#define NE     1000000  // edges
#define SCAN_T 1024
#define SCAN_TILES ((NN + SCAN_T - 1) / SCAN_T)   // 98

typedef __hip_bfloat16 bf16;

__device__ __forceinline__ float b2f(bf16 v) { return __bfloat162float(v); }
__device__ __forceinline__ bf16  f2b(float v) { return __float2bfloat16(v); }
__device__ __forceinline__ float bits2f(unsigned short h) {
    return __uint_as_float(((unsigned)h) << 16);
}
__device__ __forceinline__ float leaky(float v) { return v >= 0.f ? v : 0.01f * v; }

// dtype-adaptive scalar load
template<typename T>
__device__ __forceinline__ float ldT(const void* p, size_t i);
template<> __device__ __forceinline__ float ldT<float>(const void* p, size_t i) {
    return ((const float*)p)[i];
}
template<> __device__ __forceinline__ float ldT<bf16>(const void* p, size_t i) {
    return b2f(((const bf16*)p)[i]);
}
// dtype-adaptive float4 load/store (i multiple of 4)
template<typename T>
__device__ __forceinline__ float4 ldT4(const void* p, size_t i);
template<> __device__ __forceinline__ float4 ldT4<float>(const void* p, size_t i) {
    return *(const float4*)((const float*)p + i);
}
template<> __device__ __forceinline__ float4 ldT4<bf16>(const void* p, size_t i) {
    ushort4 u = *(const ushort4*)((const unsigned short*)p + i);
    return make_float4(bits2f(u.x), bits2f(u.y), bits2f(u.z), bits2f(u.w));
}
template<typename T>
__device__ __forceinline__ void stT4(void* p, size_t i, float4 v);
template<> __device__ __forceinline__ void stT4<float>(void* p, size_t i, float4 v) {
    *(float4*)((float*)p + i) = v;
}
template<> __device__ __forceinline__ void stT4<bf16>(void* p, size_t i, float4 v) {
    bf16 b0 = f2b(v.x), b1 = f2b(v.y), b2 = f2b(v.z), b3 = f2b(v.w);
    ushort4 u = make_ushort4(*(unsigned short*)&b0, *(unsigned short*)&b1,
                             *(unsigned short*)&b2, *(unsigned short*)&b3);
    *(ushort4*)((unsigned short*)p + i) = u;
}
__device__ __forceinline__ float4 ld4f(const float* p, size_t i) {
    return *(const float4*)(p + i);
}
// bf16 xw-table load/store (ushort bits)
__device__ __forceinline__ float4 ld4b(const unsigned short* p, size_t i) {
    ushort4 u = *(const ushort4*)(p + i);
    return make_float4(bits2f(u.x), bits2f(u.y), bits2f(u.z), bits2f(u.w));
}
__device__ __forceinline__ void st4b(unsigned short* p, size_t i, float4 v) {
    bf16 b0 = f2b(v.x), b1 = f2b(v.y), b2 = f2b(v.z), b3 = f2b(v.w);
    ushort4 u = make_ushort4(*(unsigned short*)&b0, *(unsigned short*)&b1,
                             *(unsigned short*)&b2, *(unsigned short*)&b3);
    *(ushort4*)(p + i) = u;
}
// f16 (IEEE half) x_hat table: better mantissa than bf16, same 2 B
__device__ __forceinline__ float4 ld4h(const unsigned short* p, size_t i) {
    ushort4 u = *(const ushort4*)(p + i);
    __half h0, h1, h2, h3;
    *(unsigned short*)&h0 = u.x; *(unsigned short*)&h1 = u.y;
    *(unsigned short*)&h2 = u.z; *(unsigned short*)&h3 = u.w;
    return make_float4(__half2float(h0), __half2float(h1),
                       __half2float(h2), __half2float(h3));
}
__device__ __forceinline__ void st4h(unsigned short* p, size_t i, float4 v) {
    __half h0 = __float2half(v.x), h1 = __float2half(v.y);
    __half h2 = __float2half(v.z), h3 = __float2half(v.w);
    ushort4 u = make_ushort4(*(unsigned short*)&h0, *(unsigned short*)&h1,
                             *(unsigned short*)&h2, *(unsigned short*)&h3);
    *(ushort4*)(p + i) = u;
}

// full 64-lane wave sum (float)
__device__ __forceinline__ float wred(float v) {
    for (int o = 32; o; o >>= 1) v += __shfl_xor(v, o, 64);
    return v;
}
// 16-lane group sum
__device__ __forceinline__ float gred16(float v) {
    for (int o = 8; o; o >>= 1) v += __shfl_xor(v, o, 64);
    return v;
}
// 64-lane inclusive scan (int)
__device__ __forceinline__ int wscan(int v, int lane) {
    for (int o = 1; o < 64; o <<= 1) {
        int t = __shfl_up(v, o, 64);
        v += (lane >= o) ? t : 0;
    }
    return v;
}

// ---- storage-dtype detection (bf16 vs f32 harness buffers) ----
__global__ void k_detect(const unsigned short* __restrict__ w, int* __restrict__ mode) {
    __shared__ int cnt[256];
    int bad = 0;
    for (int i = threadIdx.x; i < 4096; i += 256) {
        unsigned e = (w[i] >> 7) & 0xFFu;
        bad += (e == 0u || e == 0xFFu) ? 1 : 0;
    }
    cnt[threadIdx.x] = bad;
    __syncthreads();
    if (threadIdx.x == 0) {
        int t = 0;
        for (int k = 0; k < 256; k++) t += cnt[k];
        mode[0] = (t > 0) ? 1 : 0;   // 1 = float32 storage, 0 = bf16 storage
    }
}

// ---- transpose + f32-promote row-major weights ----
__global__ void k_prep_w(const void* umw, const void* lw1, const void* gw1,
                         const void* lw2, const void* gw2,
                         float* umwT, float* wT, const int* mode) {
    int t = blockIdx.x * 256 + threadIdx.x;   // 0 .. 24575
    bool f32m = (*mode != 0);
    if (t < 8192) {
        int j = t >> 7, k = t & 127;
        float v = f32m ? ldT<float>(umw, t) : ldT<bf16>(umw, t);
        umwT[k * 64 + j] = v;
    } else {
        int u = t - 8192;
        int m = u >> 12;          // 0..3
        int r = u & 4095;
        int j = r >> 6, k = r & 63;
        const void* srcp = (m == 0) ? lw1 : (m == 1) ? gw1 : (m == 2) ? lw2 : gw2;
        float v = f32m ? ldT<float>(srcp, r) : ldT<bf16>(srcp, r);
        wT[m * 4096 + k * 64 + j] = v;
    }
}

// ---- degree counts: out-degree over src (gate) + in-degree over dst (CSR) ----
__global__ void k_deg(const int* __restrict__ src, const int* __restrict__ dst,
                      int* __restrict__ deg, int* __restrict__ cnt) {
    int e = blockIdx.x * blockDim.x + threadIdx.x;
    if (e < NE) {
        atomicAdd(&deg[src[e]], 1);
        atomicAdd(&cnt[dst[e]], 1);
    }
}

// ---- parallel scan, pass 1: per-tile sums (+ fused dinv = rsqrt(deg)) ----
__global__ void k_scan_sum(const int* __restrict__ cnt, const int* __restrict__ deg,
                           float* __restrict__ dinv, int* __restrict__ tsum) {
    __shared__ int wsum[16];
    int i = blockIdx.x * SCAN_T + threadIdx.x;
    int lane = threadIdx.x & 63, wid = threadIdx.x >> 6;
    int v = (i < NN) ? cnt[i] : 0;
    if (i < NN) dinv[i] = rsqrtf((float)max(deg[i], 1));   // fused (was k_dinv)
    float s = wred((float)v);               // exact: counts < 2^24
    if (lane == 0) wsum[wid] = (int)s;
    __syncthreads();
    if (threadIdx.x == 0) {
        int t = 0;
        #pragma unroll
        for (int k = 0; k < 16; k++) t += wsum[k];
        tsum[blockIdx.x] = t;
    }
}

// ---- pass 2: exclusive scan of the tile sums (1 block) ----
__global__ void k_scan_tiles(const int* __restrict__ tsum, int* __restrict__ toff) {
    __shared__ int wsum[16];
    int lane = threadIdx.x & 63, wid = threadIdx.x >> 6;
    int v = (threadIdx.x < SCAN_TILES) ? tsum[threadIdx.x] : 0;
    int inc = wscan(v, lane);
    if (lane == 63) wsum[wid] = inc;
    __syncthreads();
    if (wid == 0) {
        int ws = (lane < 16) ? wsum[lane] : 0;
        int wi = wscan(ws, lane);
        if (lane < 16) wsum[lane] = wi - ws;   // exclusive wave offsets
    }
    __syncthreads();
    if (threadIdx.x < SCAN_TILES) toff[threadIdx.x] = inc - v + wsum[wid];
}

// ---- pass 3: block-local exclusive scan + tile offset -> csr_off, cursor ----
__global__ void k_scan_out(const int* __restrict__ cnt, const int* __restrict__ toff,
                           int* __restrict__ csr_off, int* __restrict__ cursor) {
    __shared__ int wsum[16];
    int i = blockIdx.x * SCAN_T + threadIdx.x;
    int lane = threadIdx.x & 63, wid = threadIdx.x >> 6;
    int v = (i < NN) ? cnt[i] : 0;
    int inc = wscan(v, lane);
    if (lane == 63) wsum[wid] = inc;
    __syncthreads();
    if (wid == 0) {
        int ws = (lane < 16) ? wsum[lane] : 0;
        int wi = wscan(ws, lane);
        if (lane < 16) wsum[lane] = wi - ws;
    }
    __syncthreads();
    int excl = inc - v + wsum[wid] + toff[blockIdx.x];
    if (i < NN) { csr_off[i] = excl; cursor[i] = excl; }
    if (i == NN - 1) csr_off[NN] = excl + v;   // == NE
}

// ---- scatter edges into dst-sorted CSR ----
__global__ void k_scatter(const int* __restrict__ src, const int* __restrict__ dst,
                          int* __restrict__ cursor, int* __restrict__ csr_src) {
    int e = blockIdx.x * blockDim.x + threadIdx.x;
    if (e < NE) {
        int pos = atomicAdd(&cursor[dst[e]], 1);
        csr_src[pos] = src[e];
    }
}

// ---- k_front_items: hop-1 front end for item nodes (proven k_pre structure).
//      normalize(feat[i]) in registers -> dual matmul from LDS Wg/lT ->
//      xw (bf16) + x_hat (f16). Grid = 80000/16 = 5000 exact.
template<typename T>
__device__ __forceinline__ void front_items_body(float4* __restrict__ gsW,
                                                 float4* __restrict__ gsL,
                                                 const void* __restrict__ feat,
                                                 const void* __restrict__ Wg,
                                                 const float* __restrict__ lT,
                                                 const void* __restrict__ lb,
                                                 const void* __restrict__ id_emb,
                                                 unsigned short* __restrict__ xw,
                                                 unsigned short* __restrict__ xhat) {
    int lane = threadIdx.x & 63, wid = threadIdx.x >> 6;
    int sl = lane & 15;
    int i = blockIdx.x * 16 + (wid << 2) + (lane >> 4);   // < 80000 (grid exact)
    // stage Wg + lT -> LDS
    #pragma unroll
    for (int t = 0; t < 4; t++) {
        int idx = threadIdx.x + t * 256;
        gsW[idx] = ldT4<T>(Wg, (size_t)idx * 4);
        gsL[idx] = ld4f(lT, (size_t)idx * 4);
    }
    size_t rb = (size_t)i * 64 + sl * 4;
    float4 v = ldT4<T>(feat, rb);
    float ss = gred16(v.x * v.x + v.y * v.y + v.z * v.z + v.w * v.w);
    float inv = 1.f / fmaxf(sqrtf(ss), 1e-12f);
    float4 xv = make_float4(v.x * inv, v.y * inv, v.z * inv, v.w * inv);
    float4 lb4 = ldT4<T>(lb, sl * 4);
    float4 id4 = ldT4<T>(id_emb, rb);
    __syncthreads();
    float4 accw = make_float4(0.f, 0.f, 0.f, 0.f);
    float4 accl = make_float4(0.f, 0.f, 0.f, 0.f);
    int gbase = lane & 48;
    #pragma unroll
    for (int kk = 0; kk < 16; kk++) {
        int srcl = gbase | kk;
        float xb[4];
        xb[0] = __shfl(xv.x, srcl, 64);
        xb[1] = __shfl(xv.y, srcl, 64);
        xb[2] = __shfl(xv.z, srcl, 64);
        xb[3] = __shfl(xv.w, srcl, 64);
        #pragma unroll
        for (int q = 0; q < 4; q++) {
            int wb = (kk * 4 + q) * 16 + sl;
            float4 w4 = gsW[wb];
            float4 l4 = gsL[wb];
            accw.x += xb[q] * w4.x; accw.y += xb[q] * w4.y;
            accw.z += xb[q] * w4.z; accw.w += xb[q] * w4.w;
            accl.x += xb[q] * l4.x; accl.y += xb[q] * l4.y;
            accl.z += xb[q] * l4.z; accl.w += xb[q] * l4.w;
        }
    }
    st4b(xw, rb, accw);
    float4 xh;
    xh.x = leaky(accl.x + lb4.x) + id4.x;
    xh.y = leaky(accl.y + lb4.y) + id4.y;
    xh.z = leaky(accl.z + lb4.z) + id4.z;
    xh.w = leaky(accl.w + lb4.w) + id4.w;
    st4h(xhat, rb, xh);
}
__global__ void k_front_items(const void* feat, const void* Wg, const float* lT,
                              const void* lb, const void* id_emb,
                              unsigned short* xw, unsigned short* xhat,
                              const int* mode) {
    __shared__ float4 gsW[1024];           // 16 KB (wrapper-hoisted: no dup)
    __shared__ float4 gsL[1024];           // 16 KB
    if (*mode) front_items_body<float>(gsW, gsL, feat, Wg, lT, lb, id_emb, xw, xhat);
    else       front_items_body<bf16>(gsW, gsL, feat, Wg, lT, lb, id_emb, xw, xhat);
}

// ---- k_front_users: hop-1 front end for user nodes.
//      REWRITTEN register-minimal (round-9 version spilled ~2.5 KB/thread ->
//      1.8 GB of scratch HBM traffic): sequential k-loop, one scalar uf
//      broadcast + one LDS float4 per step (the prep_users-proven pattern),
//      single contiguous 32 KB LDS array, no pointer select, no shuffles in
//      the MLP. Then tanh+normalize -> restage Wg/lT -> proven dual matmul.
//      Grid = 20000/16 = 1250 exact; barriers uniform per block.
template<typename T>
__device__ __forceinline__ void front_users_body(float4* __restrict__ gs,
                                                 const void* __restrict__ uf,
                                                 const float* __restrict__ umwT,
                                                 const void* __restrict__ umb,
                                                 const void* __restrict__ Wg,
                                                 const float* __restrict__ lT,
                                                 const void* __restrict__ lb,
                                                 const void* __restrict__ id_emb,
                                                 unsigned short* __restrict__ xw,
                                                 unsigned short* __restrict__ xhat) {
    int lane = threadIdx.x & 63, wid = threadIdx.x >> 6;
    int sl = lane & 15;
    int u = blockIdx.x * 16 + (wid << 2) + (lane >> 4);   // < 20000 (grid exact)
    int i = N_ITEM + u;
    int gbase = lane & 48;
    // stage umwT (128 x 64 f32 = 32 KB) contiguously: gs[k*16 + c] = umwT row k
    #pragma unroll
    for (int t = 0; t < 8; t++) {
        int idx = threadIdx.x + t * 256;           // 0..2047
        gs[idx] = ld4f(umwT, (size_t)idx * 4);
    }
    __syncthreads();
    // MLP: acc[ch] = umb[ch] + sum_k uf[u][k] * umwT[k][ch]  (ch = sl*4..sl*4+3)
    size_t ub = (size_t)u * 128;
    float4 acc = ldT4<T>(umb, sl * 4);
    #pragma unroll 4
    for (int k = 0; k < 128; k++) {
        float ufk = ldT<T>(uf, ub + k);            // uniform in 16-lane group
        float4 w4 = gs[k * 16 + sl];
        acc.x += ufk * w4.x; acc.y += ufk * w4.y;
        acc.z += ufk * w4.z; acc.w += ufk * w4.w;
    }
    float4 v = make_float4(tanhf(acc.x), tanhf(acc.y), tanhf(acc.z), tanhf(acc.w));
    float ss = gred16(v.x * v.x + v.y * v.y + v.z * v.z + v.w * v.w);
    float inv = 1.f / fmaxf(sqrtf(ss), 1e-12f);
    float4 xv = make_float4(v.x * inv, v.y * inv, v.z * inv, v.w * inv);
    __syncthreads();                       // everyone done reading umwT
    // restage: Wg -> gs[0..1023], lT -> gs[1024..2047]
    #pragma unroll
    for (int t = 0; t < 4; t++) {
        int idx = threadIdx.x + t * 256;
        gs[idx] = ldT4<T>(Wg, (size_t)idx * 4);
        gs[idx + 1024] = ld4f(lT, (size_t)idx * 4);
    }
    size_t rb = (size_t)i * 64 + sl * 4;
    float4 lb4 = ldT4<T>(lb, sl * 4);
    float4 id4 = ldT4<T>(id_emb, rb);
    __syncthreads();
    float4 accw = make_float4(0.f, 0.f, 0.f, 0.f);
    float4 accl = make_float4(0.f, 0.f, 0.f, 0.f);
    #pragma unroll
    for (int kk = 0; kk < 16; kk++) {
        int srcl = gbase | kk;
        float xb[4];
        xb[0] = __shfl(xv.x, srcl, 64);
        xb[1] = __shfl(xv.y, srcl, 64);
        xb[2] = __shfl(xv.z, srcl, 64);
        xb[3] = __shfl(xv.w, srcl, 64);
        #pragma unroll
        for (int q = 0; q < 4; q++) {
            int wb = (kk * 4 + q) * 16 + sl;
            float4 w4 = gs[wb];
            float4 l4 = gs[wb + 1024];
            accw.x += xb[q] * w4.x; accw.y += xb[q] * w4.y;
            accw.z += xb[q] * w4.z; accw.w += xb[q] * w4.w;
            accl.x += xb[q] * l4.x; accl.y += xb[q] * l4.y;
            accl.z += xb[q] * l4.z; accl.w += xb[q] * l4.w;
        }
    }
    st4b(xw, rb, accw);
    float4 xh;
    xh.x = leaky(accl.x + lb4.x) + id4.x;
    xh.y = leaky(accl.y + lb4.y) + id4.y;
    xh.z = leaky(accl.z + lb4.z) + id4.z;
    xh.w = leaky(accl.w + lb4.w) + id4.w;
    st4h(xhat, rb, xh);
}
__global__ void k_front_users(const void* uf, const float* umwT, const void* umb,
                              const void* Wg, const float* lT, const void* lb,
                              const void* id_emb,
                              unsigned short* xw, unsigned short* xhat,
                              const int* mode) {
    __shared__ float4 gs[2048];            // single 32 KB allocation (no dup)
    if (*mode) front_users_body<float>(gs, uf, umwT, umb, Wg, lT, lb,
                                       id_emb, xw, xhat);
    else       front_users_body<bf16>(gs, uf, umwT, umb, Wg, lT, lb,
                                      id_emb, xw, xhat);
}

// ---- k_pre (hop 2): xw = xin @ Wg -> bf16, x_hat -> f16; LDS weights ----
template<typename T>
__device__ __forceinline__ void pre_body(float4* __restrict__ gsW,
                                         float4* __restrict__ gsL,
                                         const float* __restrict__ xin,
                                         const void* __restrict__ Wg,
                                         const float* __restrict__ lT,
                                         const void* __restrict__ lb,
                                         const void* __restrict__ id_emb,
                                         unsigned short* __restrict__ xw,
                                         unsigned short* __restrict__ xhat) {
    int lane = threadIdx.x & 63, wid = threadIdx.x >> 6;
    int sl = lane & 15;
    int i = blockIdx.x * 16 + (wid << 2) + (lane >> 4);   // always < NN (grid exact)
    // stage both weight matrices -> LDS
    #pragma unroll
    for (int t = 0; t < 4; t++) {
        int idx = threadIdx.x + t * 256;
        gsW[idx] = ldT4<T>(Wg, (size_t)idx * 4);
        gsL[idx] = ld4f(lT, (size_t)idx * 4);
    }
    size_t rb = (size_t)i * 64 + sl * 4;
    float4 xv = ld4f(xin, rb);
    float4 lb4 = ldT4<T>(lb, sl * 4);
    float4 id4 = ldT4<T>(id_emb, rb);
    __syncthreads();
    float4 accw = make_float4(0.f, 0.f, 0.f, 0.f);
    float4 accl = make_float4(0.f, 0.f, 0.f, 0.f);
    int gbase = lane & 48;
    #pragma unroll
    for (int kk = 0; kk < 16; kk++) {
        int srcl = gbase | kk;
        float xb[4];
        xb[0] = __shfl(xv.x, srcl, 64);
        xb[1] = __shfl(xv.y, srcl, 64);
        xb[2] = __shfl(xv.z, srcl, 64);
        xb[3] = __shfl(xv.w, srcl, 64);
        #pragma unroll
        for (int q = 0; q < 4; q++) {
            int wb = (kk * 4 + q) * 16 + sl;
            float4 w4 = gsW[wb];
            float4 l4 = gsL[wb];
            accw.x += xb[q] * w4.x; accw.y += xb[q] * w4.y;
            accw.z += xb[q] * w4.z; accw.w += xb[q] * w4.w;
            accl.x += xb[q] * l4.x; accl.y += xb[q] * l4.y;
            accl.z += xb[q] * l4.z; accl.w += xb[q] * l4.w;
        }
    }
    st4b(xw, rb, accw);              // bf16 gather table
    float4 xh;
    xh.x = leaky(accl.x + lb4.x) + id4.x;
    xh.y = leaky(accl.y + lb4.y) + id4.y;
    xh.z = leaky(accl.z + lb4.z) + id4.z;
    xh.w = leaky(accl.w + lb4.w) + id4.w;
    st4h(xhat, rb, xh);              // f16 x_hat table (err ~1e-4, negligible)
}
__global__ void k_pre(const float* xin, const void* Wg, const float* lT,
                      const void* lb, const void* id_emb,
                      unsigned short* xw, unsigned short* xhat, const int* mode) {
    __shared__ float4 gsW[1024];           // 16 KB (single allocation)
    __shared__ float4 gsL[1024];           // 16 KB
    if (*mode) pre_body<float>(gsW, gsL, xin, Wg, lT, lb, id_emb, xw, xhat);
    else       pre_body<bf16>(gsW, gsL, xin, Wg, lT, lb, id_emb, xw, xhat);
}

// ---- fused GAT layer: byte-identical to the round-8 proven version ----
template<typename T>
__device__ __forceinline__ void gat_body(float4* __restrict__ gs,
                                         const unsigned short* __restrict__ xw,
                                         const unsigned short* __restrict__ xhat,
                                         const int* __restrict__ csr_off,
                                         const int* __restrict__ csr_src,
                                         const float* __restrict__ dinv,
                                         const float* __restrict__ gTg,
                                         const void* gb,
                                         float* __restrict__ xnext, void* out,
                                         int off_out) {
    int lane = threadIdx.x & 63, wid = threadIdx.x >> 6;
    int sl = lane & 15;
    int i = blockIdx.x * 16 + (wid << 2) + (lane >> 4);   // always < NN (grid exact)
    size_t rb = (size_t)i * 64 + sl * 4;
    // stage gT -> LDS (completes long before the epilogue barrier)
    #pragma unroll
    for (int t = 0; t < 4; t++)
        gs[threadIdx.x + t * 256] = ((const float4*)gTg)[threadIdx.x + t * 256];

    float4 xd = ld4b(xw, rb);
    int e0 = csr_off[i], e1 = csr_off[i + 1];
    int cnt = e1 - e0;
    float m = -1e30f, l = 0.f;
    float4 acc = make_float4(0.f, 0.f, 0.f, 0.f);
    // 2-deep software pipeline over the segment's gathers (round-0 exact)
    float4 xsA = make_float4(0.f, 0.f, 0.f, 0.f), xsB = xsA;
    float dA = 1.f, dB = 1.f;
    if (cnt > 0) {
        int s0 = csr_src[e0];
        xsA = ld4b(xw, (size_t)s0 * 64 + sl * 4);
        dA = dinv[s0];
    }
    if (cnt > 1) {
        int s1 = csr_src[e0 + 1];
        xsB = ld4b(xw, (size_t)s1 * 64 + sl * 4);
        dB = dinv[s1];
    }
    for (int t = 0; t < cnt; ++t) {
        float4 xs = xsA; float dv = dA;
        xsA = xsB; dA = dB;
        if (t + 2 < cnt) {
            int sn = csr_src[e0 + t + 2];
            xsB = ld4b(xw, (size_t)sn * 64 + sl * 4);
            dB = dinv[sn];
        }
        float p = xd.x * xs.x + xd.y * xs.y + xd.z * xs.z + xd.w * xs.w;
        float inner = gred16(p);                   // full 64-ch dot
        float gate = 1.f / (1.f + __expf(-dv * inner));
        float logit = inner * gate;
        float mn = fmaxf(m, logit);
        float sc = __expf(m - mn);                 // ==0 on first edge (m=-1e30)
        float w  = __expf(logit - mn);
        acc.x = acc.x * sc + w * xs.x;
        acc.y = acc.y * sc + w * xs.y;
        acc.z = acc.z * sc + w * xs.z;
        acc.w = acc.w * sc + w * xs.w;
        l = l * sc + w;
        m = mn;
    }
    float linv = 1.f / (l + 1e-16f);               // deg-0 dst: h = 0 (== ref)
    float4 hv = make_float4(leaky(acc.x * linv), leaky(acc.y * linv),
                            leaky(acc.z * linv), leaky(acc.w * linv));
    __syncthreads();                               // gs ready (stores long done)
    // epilogue: accg = hv @ g.T from LDS weights
    float4 accg = make_float4(0.f, 0.f, 0.f, 0.f);
    int gbase = lane & 48;
    #pragma unroll
    for (int kk = 0; kk < 16; kk++) {
        int srcl = gbase | kk;
        float hb[4];
        hb[0] = __shfl(hv.x, srcl, 64);
        hb[1] = __shfl(hv.y, srcl, 64);
        hb[2] = __shfl(hv.z, srcl, 64);
        hb[3] = __shfl(hv.w, srcl, 64);
        #pragma unroll
        for (int q = 0; q < 4; q++) {
            float4 g4 = gs[(kk * 4 + q) * 16 + sl];
            accg.x += hb[q] * g4.x; accg.y += hb[q] * g4.y;
            accg.z += hb[q] * g4.z; accg.w += hb[q] * g4.w;
        }
    }
    float4 gb4 = ldT4<T>(gb, sl * 4);
    float4 xh4 = ld4h(xhat, rb);
    float4 xn;
    xn.x = leaky(accg.x + gb4.x + xh4.x);
    xn.y = leaky(accg.y + gb4.y + xh4.y);
    xn.z = leaky(accg.z + gb4.z + xh4.z);
    xn.w = leaky(accg.w + gb4.w + xh4.w);
    if (xnext) *(float4*)(xnext + rb) = xn;
    stT4<T>(out, (size_t)i * 128 + off_out + sl * 4, xn);
}
__global__ void k_gat(const unsigned short* xw, const unsigned short* xhat,
                      const int* csr_off, const int* csr_src, const float* dinv,
                      const float* gTg, const void* gb,
                      float* xnext, void* out, int off_out, const int* mode) {
    __shared__ float4 gs[1024];            // 16 KB (single allocation)
    if (*mode) gat_body<float>(gs, xw, xhat, csr_off, csr_src, dinv, gTg, gb,
                               xnext, out, off_out);
    else       gat_body<bf16>(gs, xw, xhat, csr_off, csr_src, dinv, gTg, gb,
                              xnext, out, off_out);
}

extern "C" void kernel_launch(void* const* d_in, const int* in_sizes, int n_in,
                              void* d_out, int out_size, void* d_ws, size_t ws_size,
                              hipStream_t stream) {
    const void* feat   = d_in[0];
    const void* uf     = d_in[1];
    const void* id_emb = d_in[2];
    const void* umw    = d_in[3];
    const void* umb    = d_in[4];
    const void* gat1   = d_in[5];
    const void* lin1b  = d_in[7];
    const void* g1b    = d_in[9];
    const void* gat2   = d_in[10];
    const void* lin2b  = d_in[12];
    const void* g2b    = d_in[14];
    const int*  ei     = (const int*)d_in[15];
    const int* src = ei;
    const int* dst = ei + NE;

    // workspace layout (~83 MB; buf0 slot unused now, kept for layout stability)
    int*      mode   = (int*)d_ws;                       // 16 B slot
    int*      deg    = (int*)((char*)d_ws + 16);         // NN
    int*      cnt    = deg + NN;                         // NN (adjacent: one memset)
    int*      cursor = cnt + NN;                         // NN
    int*      csr_off = cursor + NN;                     // NN+16
    int*      tsum   = csr_off + NN + 16;                // 128
    int*      toff   = tsum + 128;                       // 128
    float*    dinv   = (float*)(toff + 128);             // NN
    float*    umwT   = dinv + NN;                        // 8192
    float*    wT     = umwT + 8192;                      // 4 x 4096
    int*      csr_src = (int*)(wT + 4 * 4096);           // NE
    float*    buf0   = (float*)(csr_src + NE);           // (unused)
    float*    buf2   = buf0 + (size_t)NN * 64;           // x1    (25.6 MB f32)
    unsigned short* xwb   = (unsigned short*)(buf2 + (size_t)NN * 64); // 12.8 MB bf16
    unsigned short* xhath = xwb + (size_t)NN * 64;       // 12.8 MB f16 x_hat

    k_detect<<<1, 256, 0, stream>>>((const unsigned short*)feat, mode);
    k_prep_w<<<96, 256, 0, stream>>>(umw, d_in[6], d_in[8], d_in[11], d_in[13],
                                     umwT, wT, mode);
    hipMemsetAsync(deg, 0, 2 * NN * 4, stream);          // deg + cnt (adjacent)
    k_deg<<<(NE + 255) / 256, 256, 0, stream>>>(src, dst, deg, cnt);
    k_scan_sum<<<SCAN_TILES, SCAN_T, 0, stream>>>(cnt, deg, dinv, tsum);
    k_scan_tiles<<<1, SCAN_T, 0, stream>>>(tsum, toff);
    k_scan_out<<<SCAN_TILES, SCAN_T, 0, stream>>>(cnt, toff, csr_off, cursor);
    k_scatter<<<(NE + 255) / 256, 256, 0, stream>>>(src, dst, cursor, csr_src);

    const float* lT1 = wT;
    const float* gT1 = wT + 4096;
    const float* lT2 = wT + 8192;
    const float* gT2 = wT + 12288;

    int nb = NN / 16;   // 6250 exactly (NN % 16 == 0) -> barriers safe

    // hop 1: feat/uf -> {xw, xhat} directly (split fused front end)
    k_front_items<<<N_ITEM / 16, 256, 0, stream>>>(feat, gat1, lT1, lin1b,
                                                   id_emb, xwb, xhath, mode);
    k_front_users<<<N_USER / 16, 256, 0, stream>>>(uf, umwT, umb, gat1, lT1,
                                                   lin1b, id_emb, xwb, xhath,
                                                   mode);
    k_gat<<<nb, 256, 0, stream>>>(xwb, xhath, csr_off, csr_src, dinv,
                                  gT1, g1b, buf2, d_out, 0, mode);
    // hop 2: x1(buf2) -> {xw, xhat} -> out cols 64..127 (x2 store skipped)
    k_pre<<<nb, 256, 0, stream>>>(buf2, gat2, lT2, lin2b, id_emb,
                                  xwb, xhath, mode);
    k_gat<<<nb, 256, 0, stream>>>(xwb, xhath, csr_off, csr_src, dinv,
                                  gT2, g2b, nullptr, d_out, 64, mode);
}